// Round 2
// baseline (2664.144 us; speedup 1.0000x reference)
//
#include <hip/hip_runtime.h>
#include <math.h>

// TriangleAttention: B=1, I=J=384, C=128, H=4, D=32, fp32 in/out.
//
// Kernel 1 (proj):  LayerNorm + {q,k,v,g} projections + tri bias.
//                   q (pre-scaled) -> d_out [I,H,J,D]; k, v, g (pre-sigmoided)
//                   -> ws [I,H,J,D]; tri -> ws [H,I,J].
// Kernel 2 (attn):  per (i,h): logits = qK^T + mask_bias + tri, softmax, o = aV,
//                   gated with g. og overwrites the g buffer in-place (each
//                   gate value is read and rewritten by the same thread).
// Kernel 3 (out):   out[i,j,c] = sum_{h,d} og[i,h,j,d] * wo[h,d,c] + bo[c];
//                   reads ws (og), writes d_out (q is dead by then).
//
// Workspace: 3 * 18,874,368 + 589,824 floats = 228,851,712 bytes (218.3 MiB).

#define I_DIM 384
#define J_DIM 384
#define C_DIM 128
#define H_DIM 4
#define D_DIM 32
#define NPOS (I_DIM * J_DIM)
#define Q_SCALE 0.17677669529663687f  // 1/sqrt(32)

__device__ __forceinline__ float sigmoidf_(float v) {
    return 1.0f / (1.0f + __expf(-v));
}

// ---------------------------------------------------------------------------
// Kernel 1: LN + projections.  grid = NPOS/64, block = 256.
// LDS: A-tile 64x128 (32KB) + B-tile 128x64 (32KB) = 64KB -> 2 blocks/CU.
// ---------------------------------------------------------------------------
__global__ __launch_bounds__(256) void proj_kernel(
    const float* __restrict__ x, const float* __restrict__ ln_g,
    const float* __restrict__ ln_b, const float* __restrict__ w_tri,
    const float* __restrict__ wq, const float* __restrict__ wk,
    const float* __restrict__ wv, const float* __restrict__ wg,
    const float* __restrict__ bg,
    float* __restrict__ qb, float* __restrict__ kb,
    float* __restrict__ vb, float* __restrict__ gb,
    float* __restrict__ tri)
{
    __shared__ float At[64 * 128];   // xn tile [m][c]
    __shared__ float Bt[128 * 64];   // weight half-chunk [c][n]

    const int t = threadIdx.x;
    const int pos0 = blockIdx.x * 64;

    // ---- LayerNorm: thread (r, part) handles row r, channels part*32..+31 ----
    {
        const int r = t >> 2, part = t & 3;
        const int c0 = part * 32;
        const float* xrow = x + (size_t)(pos0 + r) * C_DIM + c0;
        float xv[32];
        float s = 0.f, ss = 0.f;
#pragma unroll
        for (int u = 0; u < 8; ++u) {
            float4 v4 = ((const float4*)xrow)[u];
            xv[u * 4 + 0] = v4.x; xv[u * 4 + 1] = v4.y;
            xv[u * 4 + 2] = v4.z; xv[u * 4 + 3] = v4.w;
            s  += v4.x + v4.y + v4.z + v4.w;
            ss += v4.x * v4.x + v4.y * v4.y + v4.z * v4.z + v4.w * v4.w;
        }
        // reduce over the 4 threads of this row (same wave, consecutive lanes)
        s  += __shfl_xor(s, 1);  s  += __shfl_xor(s, 2);
        ss += __shfl_xor(ss, 1); ss += __shfl_xor(ss, 2);
        const float mu  = s * (1.0f / 128.0f);
        const float var = ss * (1.0f / 128.0f) - mu * mu;
        const float rstd = rsqrtf(var + 1e-5f);

        float ptri[4] = {0.f, 0.f, 0.f, 0.f};
#pragma unroll
        for (int u = 0; u < 8; ++u) {
            float4 gv = ((const float4*)(ln_g + c0))[u];
            float4 bv = ((const float4*)(ln_b + c0))[u];
            float4 xn4;
            xn4.x = (xv[u * 4 + 0] - mu) * rstd * gv.x + bv.x;
            xn4.y = (xv[u * 4 + 1] - mu) * rstd * gv.y + bv.y;
            xn4.z = (xv[u * 4 + 2] - mu) * rstd * gv.z + bv.z;
            xn4.w = (xv[u * 4 + 3] - mu) * rstd * gv.w + bv.w;
            *(float4*)(At + r * 128 + c0 + u * 4) = xn4;
            // tri partials from registers (w_tri is [c][4], 2KB, cache-resident)
#pragma unroll
            for (int q = 0; q < 4; ++q) {
                const float xnq = (q == 0) ? xn4.x : (q == 1) ? xn4.y : (q == 2) ? xn4.z : xn4.w;
                float4 wt = ((const float4*)w_tri)[c0 + u * 4 + q];
                ptri[0] += xnq * wt.x; ptri[1] += xnq * wt.y;
                ptri[2] += xnq * wt.z; ptri[3] += xnq * wt.w;
            }
        }
#pragma unroll
        for (int hh = 0; hh < 4; ++hh) {
            ptri[hh] += __shfl_xor(ptri[hh], 1);
            ptri[hh] += __shfl_xor(ptri[hh], 2);
        }
        const int pos = pos0 + r;
        const int i = pos / J_DIM, j = pos - (pos / J_DIM) * J_DIM;
        tri[((size_t)part * I_DIM + i) * J_DIM + j] = ptri[part];
    }

    // ---- GEMM: [64 x 128] x [128 x 128] for each of 4 weight matrices ----
    const int tn = t & 15, tm = t >> 4;   // 16 x 16 thread grid, 4x4 acc tile
    for (int mat = 0; mat < 4; ++mat) {
        const float* W = (mat == 0) ? wq : (mat == 1) ? wk : (mat == 2) ? wv : wg;
        float* O = (mat == 0) ? qb : (mat == 1) ? kb : (mat == 2) ? vb : gb;
        for (int nh = 0; nh < 2; ++nh) {
            __syncthreads();   // also covers At availability on first pass
#pragma unroll
            for (int u = 0; u < 8; ++u) {
                const int fi = (u * 256 + t) * 4;
                const int c = fi >> 6, nn = fi & 63;
                *(float4*)(Bt + c * 64 + nn) =
                    *(const float4*)(W + c * 128 + nh * 64 + nn);
            }
            __syncthreads();

            float4 acc[4];
#pragma unroll
            for (int mi = 0; mi < 4; ++mi) acc[mi] = make_float4(0.f, 0.f, 0.f, 0.f);

            for (int cc = 0; cc < 32; ++cc) {
                const int c = cc * 4;
                const float4 b0 = *(const float4*)(Bt + (c + 0) * 64 + tn * 4);
                const float4 b1 = *(const float4*)(Bt + (c + 1) * 64 + tn * 4);
                const float4 b2 = *(const float4*)(Bt + (c + 2) * 64 + tn * 4);
                const float4 b3 = *(const float4*)(Bt + (c + 3) * 64 + tn * 4);
#pragma unroll
                for (int mi = 0; mi < 4; ++mi) {
                    const float4 a = *(const float4*)(At + (tm * 4 + mi) * 128 + c);
                    acc[mi].x += a.x * b0.x + a.y * b1.x + a.z * b2.x + a.w * b3.x;
                    acc[mi].y += a.x * b0.y + a.y * b1.y + a.z * b2.y + a.w * b3.y;
                    acc[mi].z += a.x * b0.z + a.y * b1.z + a.z * b2.z + a.w * b3.z;
                    acc[mi].w += a.x * b0.w + a.y * b1.w + a.z * b2.w + a.w * b3.w;
                }
            }

            const int n = nh * 64 + tn * 4;
            const int h = n >> 5, d0 = n & 31;
            float4 bgv = make_float4(0.f, 0.f, 0.f, 0.f);
            if (mat == 3) bgv = *(const float4*)(bg + n);
#pragma unroll
            for (int mi = 0; mi < 4; ++mi) {
                float4 v4 = acc[mi];
                if (mat == 0) { v4.x *= Q_SCALE; v4.y *= Q_SCALE; v4.z *= Q_SCALE; v4.w *= Q_SCALE; }
                if (mat == 3) {
                    v4.x = sigmoidf_(v4.x + bgv.x); v4.y = sigmoidf_(v4.y + bgv.y);
                    v4.z = sigmoidf_(v4.z + bgv.z); v4.w = sigmoidf_(v4.w + bgv.w);
                }
                const int pos = pos0 + tm * 4 + mi;
                const int i = pos / J_DIM, j = pos - (pos / J_DIM) * J_DIM;
                *(float4*)(O + (((size_t)i * H_DIM + h) * J_DIM + j) * D_DIM + d0) = v4;
            }
        }
    }
}

// ---------------------------------------------------------------------------
// Kernel 2: attention.  grid = I*H = 1536, block = 256 (4 waves).
// LDS: Kt 32x193 (24.7KB, transposed, pad -> 2-way max) + V 192x32 (24.6KB)
//      = 49.3KB -> 3 blocks/CU.
// Each wave processes 8 q-rows per iteration; K/V halves restaged per iter.
// og overwrites gob in-place (same thread reads gate then writes output).
// ---------------------------------------------------------------------------
__global__ __launch_bounds__(256) void attn_kernel(
    const float* __restrict__ qb, const float* __restrict__ kb,
    const float* __restrict__ vb, float* gob,
    const float* __restrict__ tri, const float* __restrict__ mask)
{
    __shared__ float Kt[32 * 193];   // [d][kloc] transposed K half
    __shared__ float Vb[192 * 32];   // [kloc][d] V half

    const int t = threadIdx.x;
    const int lane = t & 63, wave = t >> 6;
    const int bid = blockIdx.x;
    const int i = bid >> 2, h = bid & 3;
    const size_t hbase = ((size_t)i * H_DIM + h) * (size_t)(J_DIM * D_DIM);

    // mask bias per lane: k = lane + 64*kk
    float mb[6];
#pragma unroll
    for (int kk = 0; kk < 6; ++kk)
        mb[kk] = 1.0e9f * (mask[i * J_DIM + lane + 64 * kk] - 1.0f);

    const int dl = lane & 31, sub = lane >> 5;

    for (int it = 0; it < 12; ++it) {
        const int r0 = it * 32 + wave * 8;

        float qv[8];
#pragma unroll
        for (int rr = 0; rr < 8; ++rr)
            qv[rr] = qb[hbase + (size_t)(r0 + rr) * D_DIM + dl];

        float lacc[8][6];
#pragma unroll
        for (int rr = 0; rr < 8; ++rr)
#pragma unroll
            for (int kk = 0; kk < 6; ++kk) lacc[rr][kk] = 0.f;

        // ---- QK^T over two K halves (half unrolled -> constant reg indices) ----
#pragma unroll
        for (int half = 0; half < 2; ++half) {
            __syncthreads();
#pragma unroll
            for (int u = 0; u < 6; ++u) {
                const int fi = (u * 256 + t) * 4;
                const int kl = fi >> 5, d0 = fi & 31;
                const float4 kv4 = *(const float4*)(
                    kb + hbase + (size_t)(half * 192 + kl) * D_DIM + d0);
                Kt[(d0 + 0) * 193 + kl] = kv4.x;
                Kt[(d0 + 1) * 193 + kl] = kv4.y;
                Kt[(d0 + 2) * 193 + kl] = kv4.z;
                Kt[(d0 + 3) * 193 + kl] = kv4.w;
            }
            __syncthreads();
#pragma unroll 4
            for (int d = 0; d < 32; ++d) {
                const float k0 = Kt[d * 193 + lane];
                const float k1 = Kt[d * 193 + lane + 64];
                const float k2 = Kt[d * 193 + lane + 128];
#pragma unroll
                for (int rr = 0; rr < 8; ++rr) {
                    const float qd = __shfl(qv[rr], d);
                    lacc[rr][half * 3 + 0] += qd * k0;
                    lacc[rr][half * 3 + 1] += qd * k1;
                    lacc[rr][half * 3 + 2] += qd * k2;
                }
            }
        }

        // ---- biases + softmax (k = lane + 64*kk across the 6 regs) ----
#pragma unroll
        for (int rr = 0; rr < 8; ++rr) {
            const float* trow = tri + ((size_t)h * I_DIM + (r0 + rr)) * J_DIM;
            float m = -1.0e30f;
#pragma unroll
            for (int kk = 0; kk < 6; ++kk) {
                lacc[rr][kk] += mb[kk] + trow[lane + 64 * kk];
                m = fmaxf(m, lacc[rr][kk]);
            }
#pragma unroll
            for (int off = 32; off >= 1; off >>= 1) m = fmaxf(m, __shfl_xor(m, off));
            float ssum = 0.f;
#pragma unroll
            for (int kk = 0; kk < 6; ++kk) {
                const float p = __expf(lacc[rr][kk] - m);
                lacc[rr][kk] = p;
                ssum += p;
            }
#pragma unroll
            for (int off = 32; off >= 1; off >>= 1) ssum += __shfl_xor(ssum, off);
            const float inv = 1.0f / ssum;
#pragma unroll
            for (int kk = 0; kk < 6; ++kk) lacc[rr][kk] *= inv;
        }

        // ---- o = a @ V; lane covers d = lane&31, sub splits k (2-way) ----
        float oacc[8];
#pragma unroll
        for (int rr = 0; rr < 8; ++rr) oacc[rr] = 0.f;

#pragma unroll
        for (int half = 0; half < 2; ++half) {
            __syncthreads();
#pragma unroll
            for (int u = 0; u < 6; ++u) {
                const int fi = (u * 256 + t) * 4;
                const int kl = fi >> 5, d0 = fi & 31;
                *(float4*)(Vb + kl * 32 + d0) = *(const float4*)(
                    vb + hbase + (size_t)(half * 192 + kl) * D_DIM + d0);
            }
            __syncthreads();
            // k-group kk2 is compile-time; src lane = jj*2+sub (192 % 64 == 0)
#pragma unroll
            for (int kk2 = 0; kk2 < 3; ++kk2) {
                for (int jj = 0; jj < 32; ++jj) {
                    const int kl = kk2 * 64 + jj * 2 + sub;
                    const float vvv = Vb[kl * 32 + dl];
                    const int sl = jj * 2 + sub;
#pragma unroll
                    for (int rr = 0; rr < 8; ++rr) {
                        const float av = __shfl(lacc[rr][half * 3 + kk2], sl);
                        oacc[rr] += av * vvv;
                    }
                }
            }
        }
#pragma unroll
        for (int rr = 0; rr < 8; ++rr) oacc[rr] += __shfl_xor(oacc[rr], 32);

        // ---- gate + store in-place (gob row owned by exactly this thread) ----
        if (lane < 32) {
#pragma unroll
            for (int rr = 0; rr < 8; ++rr) {
                const size_t idx = hbase + (size_t)(r0 + rr) * D_DIM + dl;
                gob[idx] = oacc[rr] * gob[idx];
            }
        }
    }
}

// ---------------------------------------------------------------------------
// Kernel 3: output projection.  grid = NPOS/64, block = 256.
// Reads og from ws, writes final out to d_out (q there is dead).
// ---------------------------------------------------------------------------
__global__ __launch_bounds__(256) void out_kernel(
    const float* __restrict__ og, const float* __restrict__ wo,
    const float* __restrict__ bo, float* __restrict__ out)
{
    __shared__ float At[64 * 128];
    __shared__ float Bt[128 * 64];

    const int t = threadIdx.x;
    const int pos0 = blockIdx.x * 64;

    // gather og[i, :, j, :] -> At[m][h*32+d]
    {
        const int r = t >> 2, part = t & 3;
        const int pos = pos0 + r;
        const int i = pos / J_DIM, j = pos - (pos / J_DIM) * J_DIM;
        const float* src = og + (((size_t)i * H_DIM + part) * J_DIM + j) * D_DIM;
#pragma unroll
        for (int u = 0; u < 8; ++u)
            *(float4*)(At + r * 128 + part * 32 + u * 4) = ((const float4*)src)[u];
    }

    const int tn = t & 15, tm = t >> 4;
    for (int nh = 0; nh < 2; ++nh) {
        __syncthreads();
#pragma unroll
        for (int u = 0; u < 8; ++u) {
            const int fi = (u * 256 + t) * 4;
            const int c = fi >> 6, nn = fi & 63;
            *(float4*)(Bt + c * 64 + nn) =
                *(const float4*)(wo + c * 128 + nh * 64 + nn);
        }
        __syncthreads();

        float4 acc[4];
#pragma unroll
        for (int mi = 0; mi < 4; ++mi) acc[mi] = make_float4(0.f, 0.f, 0.f, 0.f);

        for (int cc = 0; cc < 32; ++cc) {
            const int c = cc * 4;
            const float4 b0 = *(const float4*)(Bt + (c + 0) * 64 + tn * 4);
            const float4 b1 = *(const float4*)(Bt + (c + 1) * 64 + tn * 4);
            const float4 b2 = *(const float4*)(Bt + (c + 2) * 64 + tn * 4);
            const float4 b3 = *(const float4*)(Bt + (c + 3) * 64 + tn * 4);
#pragma unroll
            for (int mi = 0; mi < 4; ++mi) {
                const float4 a = *(const float4*)(At + (tm * 4 + mi) * 128 + c);
                acc[mi].x += a.x * b0.x + a.y * b1.x + a.z * b2.x + a.w * b3.x;
                acc[mi].y += a.x * b0.y + a.y * b1.y + a.z * b2.y + a.w * b3.y;
                acc[mi].z += a.x * b0.z + a.y * b1.z + a.z * b2.z + a.w * b3.z;
                acc[mi].w += a.x * b0.w + a.y * b1.w + a.z * b2.w + a.w * b3.w;
            }
        }

        const int n = nh * 64 + tn * 4;
        const float4 bov = *(const float4*)(bo + n);
#pragma unroll
        for (int mi = 0; mi < 4; ++mi) {
            float4 v4 = acc[mi];
            v4.x += bov.x; v4.y += bov.y; v4.z += bov.z; v4.w += bov.w;
            const int pos = pos0 + tm * 4 + mi;
            *(float4*)(out + (size_t)pos * C_DIM + n) = v4;
        }
    }
}

// ---------------------------------------------------------------------------
extern "C" void kernel_launch(void* const* d_in, const int* in_sizes, int n_in,
                              void* d_out, int out_size, void* d_ws, size_t ws_size,
                              hipStream_t stream)
{
    const float* x     = (const float*)d_in[0];
    const float* mask  = (const float*)d_in[1];
    const float* ln_g  = (const float*)d_in[2];
    const float* ln_b  = (const float*)d_in[3];
    const float* w_tri = (const float*)d_in[4];
    const float* wq    = (const float*)d_in[5];
    const float* wk    = (const float*)d_in[6];
    const float* wv    = (const float*)d_in[7];
    const float* wg    = (const float*)d_in[8];
    const float* bg    = (const float*)d_in[9];
    const float* wo    = (const float*)d_in[10];
    const float* bo    = (const float*)d_in[11];
    float* out = (float*)d_out;
    float* ws  = (float*)d_ws;

    const size_t NB = (size_t)NPOS * 128;  // 18,874,368 floats per buffer
    float* qb  = out;           // q staged in d_out; overwritten by out_kernel
    float* kb  = ws;
    float* vb  = ws + NB;
    float* gb  = ws + 2 * NB;   // g, then og in-place
    float* tri = ws + 3 * NB;   // [H][I][J] = 589,824 floats

    proj_kernel<<<NPOS / 64, 256, 0, stream>>>(x, ln_g, ln_b, w_tri, wq, wk, wv,
                                               wg, bg, qb, kb, vb, gb, tri);
    attn_kernel<<<I_DIM * H_DIM, 256, 0, stream>>>(qb, kb, vb, gb, tri, mask);
    out_kernel<<<NPOS / 64, 256, 0, stream>>>(gb, wo, bo, out);
}

// Round 3
// 1317.417 us; speedup vs baseline: 2.0222x; 2.0222x over previous
//
#include <hip/hip_runtime.h>
#include <math.h>

// TriangleAttention: B=1, I=J=384, C=128, H=4, D=32, fp32 in/out.
//
// Kernel 1 (proj):  LayerNorm + {q,k,v,g} projections + tri bias.
//                   q (pre-scaled) -> d_out [I,H,J,D]; k, v, g (pre-sigmoided)
//                   -> ws [I,H,J,D]; tri stored TRANSPOSED as [H][k=j][q=i]
//                   so attention's per-k read is lane-coalesced.
// Kernel 2 (attn):  block = (i,h), 192 threads; thread owns q-rows t and t+192
//                   (q, o in registers). K/V staged in LDS 96-row tiles; all
//                   inner-loop LDS reads are broadcasts (no shfl, no conflicts).
//                   Softmax: single-pass unnormalized exp (logits O(1); masked
//                   entries -1e9 -> exp = 0), per-thread scalar sum.
// Kernel 3 (out):   out[i,j,c] = sum_{h,d} og[i,h,j,d] * wo[h,d,c] + bo[c].
//
// Workspace: 3 * 18,874,368 + 589,824 floats = 228,851,712 bytes (218.3 MiB).

#define I_DIM 384
#define J_DIM 384
#define C_DIM 128
#define H_DIM 4
#define D_DIM 32
#define NPOS (I_DIM * J_DIM)
#define Q_SCALE 0.17677669529663687f  // 1/sqrt(32)

__device__ __forceinline__ float sigmoidf_(float v) {
    return 1.0f / (1.0f + __expf(-v));
}

// ---------------------------------------------------------------------------
// Kernel 1: LN + projections.  grid = NPOS/64, block = 256.
// LDS: A-tile 64x128 (32KB) + B-tile 128x64 (32KB) = 64KB -> 2 blocks/CU.
// ---------------------------------------------------------------------------
__global__ __launch_bounds__(256) void proj_kernel(
    const float* __restrict__ x, const float* __restrict__ ln_g,
    const float* __restrict__ ln_b, const float* __restrict__ w_tri,
    const float* __restrict__ wq, const float* __restrict__ wk,
    const float* __restrict__ wv, const float* __restrict__ wg,
    const float* __restrict__ bg,
    float* __restrict__ qb, float* __restrict__ kb,
    float* __restrict__ vb, float* __restrict__ gb,
    float* __restrict__ tri)
{
    __shared__ float At[64 * 128];   // xn tile [m][c]
    __shared__ float Bt[128 * 64];   // weight half-chunk [c][n]

    const int t = threadIdx.x;
    const int pos0 = blockIdx.x * 64;

    // ---- LayerNorm: thread (r, part) handles row r, channels part*32..+31 ----
    {
        const int r = t >> 2, part = t & 3;
        const int c0 = part * 32;
        const float* xrow = x + (size_t)(pos0 + r) * C_DIM + c0;
        float xv[32];
        float s = 0.f, ss = 0.f;
#pragma unroll
        for (int u = 0; u < 8; ++u) {
            float4 v4 = ((const float4*)xrow)[u];
            xv[u * 4 + 0] = v4.x; xv[u * 4 + 1] = v4.y;
            xv[u * 4 + 2] = v4.z; xv[u * 4 + 3] = v4.w;
            s  += v4.x + v4.y + v4.z + v4.w;
            ss += v4.x * v4.x + v4.y * v4.y + v4.z * v4.z + v4.w * v4.w;
        }
        // reduce over the 4 threads of this row (same wave, consecutive lanes)
        s  += __shfl_xor(s, 1);  s  += __shfl_xor(s, 2);
        ss += __shfl_xor(ss, 1); ss += __shfl_xor(ss, 2);
        const float mu  = s * (1.0f / 128.0f);
        const float var = ss * (1.0f / 128.0f) - mu * mu;
        const float rstd = rsqrtf(var + 1e-5f);

        float ptri[4] = {0.f, 0.f, 0.f, 0.f};
#pragma unroll
        for (int u = 0; u < 8; ++u) {
            float4 gv = ((const float4*)(ln_g + c0))[u];
            float4 bv = ((const float4*)(ln_b + c0))[u];
            float4 xn4;
            xn4.x = (xv[u * 4 + 0] - mu) * rstd * gv.x + bv.x;
            xn4.y = (xv[u * 4 + 1] - mu) * rstd * gv.y + bv.y;
            xn4.z = (xv[u * 4 + 2] - mu) * rstd * gv.z + bv.z;
            xn4.w = (xv[u * 4 + 3] - mu) * rstd * gv.w + bv.w;
            *(float4*)(At + r * 128 + c0 + u * 4) = xn4;
            // tri partials from registers (w_tri is [c][4], 2KB, cache-resident)
#pragma unroll
            for (int q = 0; q < 4; ++q) {
                const float xnq = (q == 0) ? xn4.x : (q == 1) ? xn4.y : (q == 2) ? xn4.z : xn4.w;
                float4 wt = ((const float4*)w_tri)[c0 + u * 4 + q];
                ptri[0] += xnq * wt.x; ptri[1] += xnq * wt.y;
                ptri[2] += xnq * wt.z; ptri[3] += xnq * wt.w;
            }
        }
#pragma unroll
        for (int hh = 0; hh < 4; ++hh) {
            ptri[hh] += __shfl_xor(ptri[hh], 1);
            ptri[hh] += __shfl_xor(ptri[hh], 2);
        }
        const int pos = pos0 + r;
        const int i = pos / J_DIM, j = pos - (pos / J_DIM) * J_DIM;
        // TRANSPOSED: tri[h][k=j][q=i]
        tri[((size_t)part * J_DIM + j) * I_DIM + i] = ptri[part];
    }

    // ---- GEMM: [64 x 128] x [128 x 128] for each of 4 weight matrices ----
    const int tn = t & 15, tm = t >> 4;   // 16 x 16 thread grid, 4x4 acc tile
    for (int mat = 0; mat < 4; ++mat) {
        const float* W = (mat == 0) ? wq : (mat == 1) ? wk : (mat == 2) ? wv : wg;
        float* O = (mat == 0) ? qb : (mat == 1) ? kb : (mat == 2) ? vb : gb;
        for (int nh = 0; nh < 2; ++nh) {
            __syncthreads();   // also covers At availability on first pass
#pragma unroll
            for (int u = 0; u < 8; ++u) {
                const int fi = (u * 256 + t) * 4;
                const int c = fi >> 6, nn = fi & 63;
                *(float4*)(Bt + c * 64 + nn) =
                    *(const float4*)(W + c * 128 + nh * 64 + nn);
            }
            __syncthreads();

            float4 acc[4];
#pragma unroll
            for (int mi = 0; mi < 4; ++mi) acc[mi] = make_float4(0.f, 0.f, 0.f, 0.f);

            for (int cc = 0; cc < 32; ++cc) {
                const int c = cc * 4;
                const float4 b0 = *(const float4*)(Bt + (c + 0) * 64 + tn * 4);
                const float4 b1 = *(const float4*)(Bt + (c + 1) * 64 + tn * 4);
                const float4 b2 = *(const float4*)(Bt + (c + 2) * 64 + tn * 4);
                const float4 b3 = *(const float4*)(Bt + (c + 3) * 64 + tn * 4);
#pragma unroll
                for (int mi = 0; mi < 4; ++mi) {
                    const float4 a = *(const float4*)(At + (tm * 4 + mi) * 128 + c);
                    acc[mi].x += a.x * b0.x + a.y * b1.x + a.z * b2.x + a.w * b3.x;
                    acc[mi].y += a.x * b0.y + a.y * b1.y + a.z * b2.y + a.w * b3.y;
                    acc[mi].z += a.x * b0.z + a.y * b1.z + a.z * b2.z + a.w * b3.z;
                    acc[mi].w += a.x * b0.w + a.y * b1.w + a.z * b2.w + a.w * b3.w;
                }
            }

            const int n = nh * 64 + tn * 4;
            const int h = n >> 5, d0 = n & 31;
            float4 bgv = make_float4(0.f, 0.f, 0.f, 0.f);
            if (mat == 3) bgv = *(const float4*)(bg + n);
#pragma unroll
            for (int mi = 0; mi < 4; ++mi) {
                float4 v4 = acc[mi];
                if (mat == 0) { v4.x *= Q_SCALE; v4.y *= Q_SCALE; v4.z *= Q_SCALE; v4.w *= Q_SCALE; }
                if (mat == 3) {
                    v4.x = sigmoidf_(v4.x + bgv.x); v4.y = sigmoidf_(v4.y + bgv.y);
                    v4.z = sigmoidf_(v4.z + bgv.z); v4.w = sigmoidf_(v4.w + bgv.w);
                }
                const int pos = pos0 + tm * 4 + mi;
                const int i = pos / J_DIM, j = pos - (pos / J_DIM) * J_DIM;
                *(float4*)(O + (((size_t)i * H_DIM + h) * J_DIM + j) * D_DIM + d0) = v4;
            }
        }
    }
}

// ---------------------------------------------------------------------------
// Kernel 2: attention, shfl-free.  grid = I*H = 1536, block = 192 (3 waves).
// Thread owns q-rows t and t+192. K/V LDS tiles of 96 rows (24.6KB).
// All inner LDS reads are wave-broadcasts (conflict-free).
// ---------------------------------------------------------------------------
__global__ __launch_bounds__(192) void attn_kernel(
    const float* __restrict__ qb, const float* __restrict__ kb,
    const float* __restrict__ vb, float* gob,
    const float* __restrict__ triT, const float* __restrict__ mask)
{
    __shared__ float Kt[96 * 32];
    __shared__ float Vt[96 * 32];
    __shared__ float Mb[J_DIM];

    const int t = threadIdx.x;
    const int bid = blockIdx.x;
    const int i = bid >> 2, h = bid & 3;
    const size_t hbase = ((size_t)i * H_DIM + h) * (size_t)(J_DIM * D_DIM);

    // mask bias (uniform per block) into LDS
    for (int idx = t; idx < J_DIM; idx += 192)
        Mb[idx] = 1.0e9f * (mask[i * J_DIM + idx] - 1.0f);

    // q rows owned by this thread (pre-scaled by proj)
    float q0[32], q1[32];
    {
        const float4* s0p = (const float4*)(qb + hbase + (size_t)t * D_DIM);
        const float4* s1p = (const float4*)(qb + hbase + (size_t)(t + 192) * D_DIM);
#pragma unroll
        for (int u = 0; u < 8; ++u) {
            float4 a = s0p[u], b = s1p[u];
            q0[u * 4 + 0] = a.x; q0[u * 4 + 1] = a.y; q0[u * 4 + 2] = a.z; q0[u * 4 + 3] = a.w;
            q1[u * 4 + 0] = b.x; q1[u * 4 + 1] = b.y; q1[u * 4 + 2] = b.z; q1[u * 4 + 3] = b.w;
        }
    }

    float o0[32], o1[32];
#pragma unroll
    for (int u = 0; u < 32; ++u) { o0[u] = 0.f; o1[u] = 0.f; }
    float s0 = 0.f, s1 = 0.f;

    const float* triH = triT + (size_t)h * J_DIM * I_DIM;
    // prefetch tri for k = 0 (coalesced: lane -> consecutive q)
    float tri0 = triH[t];
    float tri1 = triH[t + 192];

    for (int tile = 0; tile < 4; ++tile) {
        __syncthreads();
#pragma unroll
        for (int u = 0; u < 4; ++u) {
            const int fidx = u * 192 + t;   // 768 float4 per buffer
            ((float4*)Kt)[fidx] = ((const float4*)(kb + hbase + tile * (96 * D_DIM)))[fidx];
            ((float4*)Vt)[fidx] = ((const float4*)(vb + hbase + tile * (96 * D_DIM)))[fidx];
        }
        __syncthreads();

        for (int kk = 0; kk < 96; ++kk) {
            const int k = tile * 96 + kk;
            // prefetch tri for next k (hides global latency behind the dot)
            const int kn = (k + 1 < J_DIM) ? (k + 1) : k;
            const float tri0n = triH[(size_t)kn * I_DIM + t];
            const float tri1n = triH[(size_t)kn * I_DIM + t + 192];

            float l0 = 0.f, l1 = 0.f;
            const float4* kp = (const float4*)(Kt + kk * D_DIM);
#pragma unroll
            for (int u = 0; u < 8; ++u) {
                const float4 k4 = kp[u];
                l0 += q0[u * 4 + 0] * k4.x + q0[u * 4 + 1] * k4.y
                    + q0[u * 4 + 2] * k4.z + q0[u * 4 + 3] * k4.w;
                l1 += q1[u * 4 + 0] * k4.x + q1[u * 4 + 1] * k4.y
                    + q1[u * 4 + 2] * k4.z + q1[u * 4 + 3] * k4.w;
            }
            const float mbk = Mb[k];
            const float p0 = __expf(l0 + mbk + tri0);
            const float p1 = __expf(l1 + mbk + tri1);
            tri0 = tri0n; tri1 = tri1n;
            s0 += p0; s1 += p1;

            const float4* vp = (const float4*)(Vt + kk * D_DIM);
#pragma unroll
            for (int u = 0; u < 8; ++u) {
                const float4 v4 = vp[u];
                o0[u * 4 + 0] += p0 * v4.x; o0[u * 4 + 1] += p0 * v4.y;
                o0[u * 4 + 2] += p0 * v4.z; o0[u * 4 + 3] += p0 * v4.w;
                o1[u * 4 + 0] += p1 * v4.x; o1[u * 4 + 1] += p1 * v4.y;
                o1[u * 4 + 2] += p1 * v4.z; o1[u * 4 + 3] += p1 * v4.w;
            }
        }
    }

    // epilogue: normalize, gate (in-place: this thread owns these rows)
    const float inv0 = 1.0f / s0;
    const float inv1 = 1.0f / s1;
    {
        float4* d0 = (float4*)(gob + hbase + (size_t)t * D_DIM);
#pragma unroll
        for (int u = 0; u < 8; ++u) {
            float4 g4 = d0[u];
            g4.x = o0[u * 4 + 0] * inv0 * g4.x; g4.y = o0[u * 4 + 1] * inv0 * g4.y;
            g4.z = o0[u * 4 + 2] * inv0 * g4.z; g4.w = o0[u * 4 + 3] * inv0 * g4.w;
            d0[u] = g4;
        }
        float4* d1 = (float4*)(gob + hbase + (size_t)(t + 192) * D_DIM);
#pragma unroll
        for (int u = 0; u < 8; ++u) {
            float4 g4 = d1[u];
            g4.x = o1[u * 4 + 0] * inv1 * g4.x; g4.y = o1[u * 4 + 1] * inv1 * g4.y;
            g4.z = o1[u * 4 + 2] * inv1 * g4.z; g4.w = o1[u * 4 + 3] * inv1 * g4.w;
            d1[u] = g4;
        }
    }
}

// ---------------------------------------------------------------------------
// Kernel 3: output projection.  grid = NPOS/64, block = 256.
// Reads og from ws, writes final out to d_out (q there is dead).
// ---------------------------------------------------------------------------
__global__ __launch_bounds__(256) void out_kernel(
    const float* __restrict__ og, const float* __restrict__ wo,
    const float* __restrict__ bo, float* __restrict__ out)
{
    __shared__ float At[64 * 128];
    __shared__ float Bt[128 * 64];

    const int t = threadIdx.x;
    const int pos0 = blockIdx.x * 64;

    // gather og[i, :, j, :] -> At[m][h*32+d]
    {
        const int r = t >> 2, part = t & 3;
        const int pos = pos0 + r;
        const int i = pos / J_DIM, j = pos - (pos / J_DIM) * J_DIM;
        const float* src = og + (((size_t)i * H_DIM + part) * J_DIM + j) * D_DIM;
#pragma unroll
        for (int u = 0; u < 8; ++u)
            *(float4*)(At + r * 128 + part * 32 + u * 4) = ((const float4*)src)[u];
    }

    const int tn = t & 15, tm = t >> 4;
    for (int nh = 0; nh < 2; ++nh) {
        __syncthreads();
#pragma unroll
        for (int u = 0; u < 8; ++u) {
            const int fi = (u * 256 + t) * 4;
            const int c = fi >> 6, nn = fi & 63;
            *(float4*)(Bt + c * 64 + nn) =
                *(const float4*)(wo + c * 128 + nh * 64 + nn);
        }
        __syncthreads();

        float4 acc[4];
#pragma unroll
        for (int mi = 0; mi < 4; ++mi) acc[mi] = make_float4(0.f, 0.f, 0.f, 0.f);

        for (int cc = 0; cc < 32; ++cc) {
            const int c = cc * 4;
            const float4 b0 = *(const float4*)(Bt + (c + 0) * 64 + tn * 4);
            const float4 b1 = *(const float4*)(Bt + (c + 1) * 64 + tn * 4);
            const float4 b2 = *(const float4*)(Bt + (c + 2) * 64 + tn * 4);
            const float4 b3 = *(const float4*)(Bt + (c + 3) * 64 + tn * 4);
#pragma unroll
            for (int mi = 0; mi < 4; ++mi) {
                const float4 a = *(const float4*)(At + (tm * 4 + mi) * 128 + c);
                acc[mi].x += a.x * b0.x + a.y * b1.x + a.z * b2.x + a.w * b3.x;
                acc[mi].y += a.x * b0.y + a.y * b1.y + a.z * b2.y + a.w * b3.y;
                acc[mi].z += a.x * b0.z + a.y * b1.z + a.z * b2.z + a.w * b3.z;
                acc[mi].w += a.x * b0.w + a.y * b1.w + a.z * b2.w + a.w * b3.w;
            }
        }

        const int n = nh * 64 + tn * 4;
        const float4 bov = *(const float4*)(bo + n);
#pragma unroll
        for (int mi = 0; mi < 4; ++mi) {
            float4 v4 = acc[mi];
            v4.x += bov.x; v4.y += bov.y; v4.z += bov.z; v4.w += bov.w;
            const int pos = pos0 + tm * 4 + mi;
            *(float4*)(out + (size_t)pos * C_DIM + n) = v4;
        }
    }
}

// ---------------------------------------------------------------------------
extern "C" void kernel_launch(void* const* d_in, const int* in_sizes, int n_in,
                              void* d_out, int out_size, void* d_ws, size_t ws_size,
                              hipStream_t stream)
{
    const float* x     = (const float*)d_in[0];
    const float* mask  = (const float*)d_in[1];
    const float* ln_g  = (const float*)d_in[2];
    const float* ln_b  = (const float*)d_in[3];
    const float* w_tri = (const float*)d_in[4];
    const float* wq    = (const float*)d_in[5];
    const float* wk    = (const float*)d_in[6];
    const float* wv    = (const float*)d_in[7];
    const float* wg    = (const float*)d_in[8];
    const float* bg    = (const float*)d_in[9];
    const float* wo    = (const float*)d_in[10];
    const float* bo    = (const float*)d_in[11];
    float* out = (float*)d_out;
    float* ws  = (float*)d_ws;

    const size_t NB = (size_t)NPOS * 128;  // 18,874,368 floats per buffer
    float* qb  = out;           // q staged in d_out; overwritten by out_kernel
    float* kb  = ws;
    float* vb  = ws + NB;
    float* gb  = ws + 2 * NB;   // g, then og in-place
    float* tri = ws + 3 * NB;   // TRANSPOSED [H][J][I] = 589,824 floats

    proj_kernel<<<NPOS / 64, 256, 0, stream>>>(x, ln_g, ln_b, w_tri, wq, wk, wv,
                                               wg, bg, qb, kb, vb, gb, tri);
    attn_kernel<<<I_DIM * H_DIM, 192, 0, stream>>>(qb, kb, vb, gb, tri, mask);
    out_kernel<<<NPOS / 64, 256, 0, stream>>>(gb, wo, bo, out);
}

// Round 4
// 727.767 us; speedup vs baseline: 3.6607x; 1.8102x over previous
//
#include <hip/hip_runtime.h>
#include <math.h>

// TriangleAttention: B=1, I=J=384, C=128, H=4, D=32, fp32 in/out.
//
// Kernel 1 (proj): LayerNorm + {q,k,v,g} projections + tri bias.
//   q (pre-scaled), k, v -> BF16 [i][h][j][d] in ws; g (pre-sigmoided) fp32;
//   tri fp32 stored [h][k=j][q=i] (so attention's bias read is a float4 over q).
// Kernel 2 (attn): MFMA flash attention. Block = (i,h), 256 thr (4 waves),
//   wave owns 96 q-rows. Per 64-k tile: S = Q.K^T (mfma 16x16x32 bf16, C-layout
//   col=lane&15=k, row=quad*4+reg=q), + mask/tri bias, unnormalized exp
//   (masked -> exp(-1e9)=0; no max pass), P->LDS (bf16, wave-private, pad 68),
//   O += P.V via mfma with V transposed [d][kpos] in LDS. Row sums via
//   in-register accumulation + one 16-lane butterfly at the end.
// Kernel 3 (out): out = og . wo + bo (unchanged fp32 tile GEMM).
//
// Workspace: 3 bf16 buffers (36 MiB ea) + g fp32 (72 MiB) + tri (2.25 MiB).

#define I_DIM 384
#define J_DIM 384
#define C_DIM 128
#define H_DIM 4
#define D_DIM 32
#define NPOS (I_DIM * J_DIM)
#define Q_SCALE 0.17677669529663687f  // 1/sqrt(32)

typedef __attribute__((ext_vector_type(8))) short bf16x8;
typedef __attribute__((ext_vector_type(4))) float f32x4;

__device__ __forceinline__ float sigmoidf_(float v) {
    return 1.0f / (1.0f + __expf(-v));
}

__device__ __forceinline__ unsigned short f2bf(float f) {
    union { float f; unsigned u; } x; x.f = f;
    unsigned u = x.u;
    u += 0x7fffu + ((u >> 16) & 1u);   // round-to-nearest-even
    return (unsigned short)(u >> 16);
}

// ---------------------------------------------------------------------------
// Kernel 1: LN + projections.  grid = NPOS/64, block = 256.
// ---------------------------------------------------------------------------
__global__ __launch_bounds__(256) void proj_kernel(
    const float* __restrict__ x, const float* __restrict__ ln_g,
    const float* __restrict__ ln_b, const float* __restrict__ w_tri,
    const float* __restrict__ wq, const float* __restrict__ wk,
    const float* __restrict__ wv, const float* __restrict__ wg,
    const float* __restrict__ bg,
    unsigned short* __restrict__ qb, unsigned short* __restrict__ kb,
    unsigned short* __restrict__ vb, float* __restrict__ gb,
    float* __restrict__ tri)
{
    __shared__ float At[64 * 128];   // xn tile [m][c]
    __shared__ float Bt[128 * 64];   // weight half-chunk [c][n]

    const int t = threadIdx.x;
    const int pos0 = blockIdx.x * 64;

    // ---- LayerNorm: thread (r, part) handles row r, channels part*32..+31 ----
    {
        const int r = t >> 2, part = t & 3;
        const int c0 = part * 32;
        const float* xrow = x + (size_t)(pos0 + r) * C_DIM + c0;
        float xv[32];
        float s = 0.f, ss = 0.f;
#pragma unroll
        for (int u = 0; u < 8; ++u) {
            float4 v4 = ((const float4*)xrow)[u];
            xv[u * 4 + 0] = v4.x; xv[u * 4 + 1] = v4.y;
            xv[u * 4 + 2] = v4.z; xv[u * 4 + 3] = v4.w;
            s  += v4.x + v4.y + v4.z + v4.w;
            ss += v4.x * v4.x + v4.y * v4.y + v4.z * v4.z + v4.w * v4.w;
        }
        s  += __shfl_xor(s, 1);  s  += __shfl_xor(s, 2);
        ss += __shfl_xor(ss, 1); ss += __shfl_xor(ss, 2);
        const float mu  = s * (1.0f / 128.0f);
        const float var = ss * (1.0f / 128.0f) - mu * mu;
        const float rstd = rsqrtf(var + 1e-5f);

        float ptri[4] = {0.f, 0.f, 0.f, 0.f};
#pragma unroll
        for (int u = 0; u < 8; ++u) {
            float4 gv = ((const float4*)(ln_g + c0))[u];
            float4 bv = ((const float4*)(ln_b + c0))[u];
            float4 xn4;
            xn4.x = (xv[u * 4 + 0] - mu) * rstd * gv.x + bv.x;
            xn4.y = (xv[u * 4 + 1] - mu) * rstd * gv.y + bv.y;
            xn4.z = (xv[u * 4 + 2] - mu) * rstd * gv.z + bv.z;
            xn4.w = (xv[u * 4 + 3] - mu) * rstd * gv.w + bv.w;
            *(float4*)(At + r * 128 + c0 + u * 4) = xn4;
#pragma unroll
            for (int q = 0; q < 4; ++q) {
                const float xnq = (q == 0) ? xn4.x : (q == 1) ? xn4.y : (q == 2) ? xn4.z : xn4.w;
                float4 wt = ((const float4*)w_tri)[c0 + u * 4 + q];
                ptri[0] += xnq * wt.x; ptri[1] += xnq * wt.y;
                ptri[2] += xnq * wt.z; ptri[3] += xnq * wt.w;
            }
        }
#pragma unroll
        for (int hh = 0; hh < 4; ++hh) {
            ptri[hh] += __shfl_xor(ptri[hh], 1);
            ptri[hh] += __shfl_xor(ptri[hh], 2);
        }
        const int pos = pos0 + r;
        const int i = pos / J_DIM, j = pos - (pos / J_DIM) * J_DIM;
        // tri[h][k=j][q=i]
        tri[((size_t)part * J_DIM + j) * I_DIM + i] = ptri[part];
    }

    // ---- GEMM: [64 x 128] x [128 x 128] for each of 4 weight matrices ----
    const int tn = t & 15, tm = t >> 4;
    for (int mat = 0; mat < 4; ++mat) {
        const float* W = (mat == 0) ? wq : (mat == 1) ? wk : (mat == 2) ? wv : wg;
        for (int nh = 0; nh < 2; ++nh) {
            __syncthreads();
#pragma unroll
            for (int u = 0; u < 8; ++u) {
                const int fi = (u * 256 + t) * 4;
                const int c = fi >> 6, nn = fi & 63;
                *(float4*)(Bt + c * 64 + nn) =
                    *(const float4*)(W + c * 128 + nh * 64 + nn);
            }
            __syncthreads();

            float4 acc[4];
#pragma unroll
            for (int mi = 0; mi < 4; ++mi) acc[mi] = make_float4(0.f, 0.f, 0.f, 0.f);

            for (int cc = 0; cc < 32; ++cc) {
                const int c = cc * 4;
                const float4 b0 = *(const float4*)(Bt + (c + 0) * 64 + tn * 4);
                const float4 b1 = *(const float4*)(Bt + (c + 1) * 64 + tn * 4);
                const float4 b2 = *(const float4*)(Bt + (c + 2) * 64 + tn * 4);
                const float4 b3 = *(const float4*)(Bt + (c + 3) * 64 + tn * 4);
#pragma unroll
                for (int mi = 0; mi < 4; ++mi) {
                    const float4 a = *(const float4*)(At + (tm * 4 + mi) * 128 + c);
                    acc[mi].x += a.x * b0.x + a.y * b1.x + a.z * b2.x + a.w * b3.x;
                    acc[mi].y += a.x * b0.y + a.y * b1.y + a.z * b2.y + a.w * b3.y;
                    acc[mi].z += a.x * b0.z + a.y * b1.z + a.z * b2.z + a.w * b3.z;
                    acc[mi].w += a.x * b0.w + a.y * b1.w + a.z * b2.w + a.w * b3.w;
                }
            }

            const int n = nh * 64 + tn * 4;
            const int h = n >> 5, d0 = n & 31;
            float4 bgv = make_float4(0.f, 0.f, 0.f, 0.f);
            if (mat == 3) bgv = *(const float4*)(bg + n);
#pragma unroll
            for (int mi = 0; mi < 4; ++mi) {
                float4 v4 = acc[mi];
                const int pos = pos0 + tm * 4 + mi;
                const int i = pos / J_DIM, j = pos - (pos / J_DIM) * J_DIM;
                const size_t eidx = (((size_t)i * H_DIM + h) * J_DIM + j) * D_DIM + d0;
                if (mat == 3) {
                    v4.x = sigmoidf_(v4.x + bgv.x); v4.y = sigmoidf_(v4.y + bgv.y);
                    v4.z = sigmoidf_(v4.z + bgv.z); v4.w = sigmoidf_(v4.w + bgv.w);
                    *(float4*)(gb + eidx) = v4;
                } else {
                    if (mat == 0) { v4.x *= Q_SCALE; v4.y *= Q_SCALE; v4.z *= Q_SCALE; v4.w *= Q_SCALE; }
                    unsigned short* O = (mat == 0) ? qb : (mat == 1) ? kb : vb;
                    ushort4 h4;
                    h4.x = f2bf(v4.x); h4.y = f2bf(v4.y);
                    h4.z = f2bf(v4.z); h4.w = f2bf(v4.w);
                    *(ushort4*)(O + eidx) = h4;
                }
            }
        }
    }
}

// ---------------------------------------------------------------------------
// Kernel 2: MFMA attention.  grid = I*H = 1536, block = 256 (4 waves).
// LDS: Klds 64x32 bf16 (4KB) + Vt 32x68 bf16 (4.25KB) + Plds 4x96x68 bf16
//      (52.2KB) + Mb (1.5KB) = ~62KB -> 2 blocks/CU.
// ---------------------------------------------------------------------------
__global__ __launch_bounds__(256) void attn_kernel(
    const unsigned short* __restrict__ qb, const unsigned short* __restrict__ kb,
    const unsigned short* __restrict__ vb, float* gob,
    const float* __restrict__ triT, const float* __restrict__ mask)
{
    __shared__ unsigned short Klds[64 * 32];
    __shared__ unsigned short Vt[32 * 68];
    __shared__ unsigned short Plds[4][96 * 68];
    __shared__ float Mb[J_DIM];

    const int t = threadIdx.x;
    const int lane = t & 63, wave = t >> 6;
    const int q15 = lane & 15, quad = lane >> 4;
    const int i = blockIdx.x >> 2, h = blockIdx.x & 3;
    const size_t hb = (size_t)(i * H_DIM + h) * (J_DIM * D_DIM);
    const int m0 = wave * 96;

    for (int idx = t; idx < J_DIM; idx += 256)
        Mb[idx] = 1.0e9f * (mask[i * J_DIM + idx] - 1.0f);

    // Q A-frags: A[m = lane&15][k(d) = quad*8 + j]
    bf16x8 qf[6];
#pragma unroll
    for (int m = 0; m < 6; ++m)
        qf[m] = *(const bf16x8*)(qb + hb + (size_t)(m0 + m * 16 + q15) * D_DIM + quad * 8);

    f32x4 Oacc[6][2];
    float sums[6][4];
#pragma unroll
    for (int m = 0; m < 6; ++m) {
#pragma unroll
        for (int d2 = 0; d2 < 2; ++d2) Oacc[m][d2] = (f32x4){0.f, 0.f, 0.f, 0.f};
#pragma unroll
        for (int r = 0; r < 4; ++r) sums[m][r] = 0.f;
    }

    unsigned short* Pw = Plds[wave];
    const float* triH = triT + (size_t)h * J_DIM * I_DIM;

    for (int kt = 0; kt < 6; ++kt) {
        __syncthreads();
        // ---- stage K (natural [kpos][d]) and V transposed ([d][kpos], pad 68)
        {
            const int kp = t >> 2, du = (t & 3) * 8;
            const size_t gsrc = hb + (size_t)(kt * 64 + kp) * D_DIM + du;
            *(int4*)&Klds[kp * 32 + du] = *(const int4*)(kb + gsrc);
            int4 vv = *(const int4*)(vb + gsrc);
            const unsigned short* vs = (const unsigned short*)&vv;
#pragma unroll
            for (int u = 0; u < 8; ++u)
                Vt[(du + u) * 68 + kp] = vs[u];
        }
        __syncthreads();

        // ---- S = Q.K^T, bias, exp, P -> LDS (wave-private) ----
#pragma unroll
        for (int nt = 0; nt < 4; ++nt) {
            const bf16x8 kf = *(const bf16x8*)&Klds[(nt * 16 + q15) * 32 + quad * 8];
            const float mb = Mb[kt * 64 + nt * 16 + q15];
            const float* tcol = triH + (size_t)(kt * 64 + nt * 16 + q15) * I_DIM;
#pragma unroll
            for (int m = 0; m < 6; ++m) {
                const float4 tb = *(const float4*)(tcol + m0 + m * 16 + quad * 4);
                f32x4 s = {0.f, 0.f, 0.f, 0.f};
                s = __builtin_amdgcn_mfma_f32_16x16x32_bf16(qf[m], kf, s, 0, 0, 0);
                const float p0 = __expf(s[0] + mb + tb.x);
                const float p1 = __expf(s[1] + mb + tb.y);
                const float p2 = __expf(s[2] + mb + tb.z);
                const float p3 = __expf(s[3] + mb + tb.w);
                sums[m][0] += p0; sums[m][1] += p1;
                sums[m][2] += p2; sums[m][3] += p3;
                const int row = m * 16 + quad * 4;
                const int col = nt * 16 + q15;
                Pw[(row + 0) * 68 + col] = f2bf(p0);
                Pw[(row + 1) * 68 + col] = f2bf(p1);
                Pw[(row + 2) * 68 + col] = f2bf(p2);
                Pw[(row + 3) * 68 + col] = f2bf(p3);
            }
        }

        // ---- O += P.V  (A = P from Plds rows, B = V from Vt rows) ----
        bf16x8 vf[2][2];
#pragma unroll
        for (int ks = 0; ks < 2; ++ks)
#pragma unroll
            for (int d2 = 0; d2 < 2; ++d2)
                vf[ks][d2] = *(const bf16x8*)&Vt[(d2 * 16 + q15) * 68 + ks * 32 + quad * 8];
#pragma unroll
        for (int m = 0; m < 6; ++m) {
#pragma unroll
            for (int ks = 0; ks < 2; ++ks) {
                const bf16x8 af = *(const bf16x8*)&Pw[(m * 16 + q15) * 68 + ks * 32 + quad * 8];
                Oacc[m][0] = __builtin_amdgcn_mfma_f32_16x16x32_bf16(af, vf[ks][0], Oacc[m][0], 0, 0, 0);
                Oacc[m][1] = __builtin_amdgcn_mfma_f32_16x16x32_bf16(af, vf[ks][1], Oacc[m][1], 0, 0, 0);
            }
        }
    }

    // ---- row sums: butterfly over the 16 k-lanes of each quad ----
    float inv[6][4];
#pragma unroll
    for (int m = 0; m < 6; ++m)
#pragma unroll
        for (int r = 0; r < 4; ++r) {
            float s0 = sums[m][r];
            s0 += __shfl_xor(s0, 1); s0 += __shfl_xor(s0, 2);
            s0 += __shfl_xor(s0, 4); s0 += __shfl_xor(s0, 8);
            inv[m][r] = 1.0f / s0;
        }

    // ---- normalize, gate, store (in-place over g; rows owned per-lane) ----
#pragma unroll
    for (int m = 0; m < 6; ++m) {
        const int qrow = m0 + m * 16 + quad * 4;
#pragma unroll
        for (int d2 = 0; d2 < 2; ++d2) {
            const int d = d2 * 16 + q15;
#pragma unroll
            for (int r = 0; r < 4; ++r) {
                const size_t idx = hb + (size_t)(qrow + r) * D_DIM + d;
                gob[idx] = Oacc[m][d2][r] * inv[m][r] * gob[idx];
            }
        }
    }
}

// ---------------------------------------------------------------------------
// Kernel 3: output projection.  grid = NPOS/64, block = 256.
// ---------------------------------------------------------------------------
__global__ __launch_bounds__(256) void out_kernel(
    const float* __restrict__ og, const float* __restrict__ wo,
    const float* __restrict__ bo, float* __restrict__ out)
{
    __shared__ float At[64 * 128];
    __shared__ float Bt[128 * 64];

    const int t = threadIdx.x;
    const int pos0 = blockIdx.x * 64;

    {
        const int r = t >> 2, part = t & 3;
        const int pos = pos0 + r;
        const int i = pos / J_DIM, j = pos - (pos / J_DIM) * J_DIM;
        const float* src = og + (((size_t)i * H_DIM + part) * J_DIM + j) * D_DIM;
#pragma unroll
        for (int u = 0; u < 8; ++u)
            *(float4*)(At + r * 128 + part * 32 + u * 4) = ((const float4*)src)[u];
    }

    const int tn = t & 15, tm = t >> 4;
    for (int nh = 0; nh < 2; ++nh) {
        __syncthreads();
#pragma unroll
        for (int u = 0; u < 8; ++u) {
            const int fi = (u * 256 + t) * 4;
            const int c = fi >> 6, nn = fi & 63;
            *(float4*)(Bt + c * 64 + nn) =
                *(const float4*)(wo + c * 128 + nh * 64 + nn);
        }
        __syncthreads();

        float4 acc[4];
#pragma unroll
        for (int mi = 0; mi < 4; ++mi) acc[mi] = make_float4(0.f, 0.f, 0.f, 0.f);

        for (int cc = 0; cc < 32; ++cc) {
            const int c = cc * 4;
            const float4 b0 = *(const float4*)(Bt + (c + 0) * 64 + tn * 4);
            const float4 b1 = *(const float4*)(Bt + (c + 1) * 64 + tn * 4);
            const float4 b2 = *(const float4*)(Bt + (c + 2) * 64 + tn * 4);
            const float4 b3 = *(const float4*)(Bt + (c + 3) * 64 + tn * 4);
#pragma unroll
            for (int mi = 0; mi < 4; ++mi) {
                const float4 a = *(const float4*)(At + (tm * 4 + mi) * 128 + c);
                acc[mi].x += a.x * b0.x + a.y * b1.x + a.z * b2.x + a.w * b3.x;
                acc[mi].y += a.x * b0.y + a.y * b1.y + a.z * b2.y + a.w * b3.y;
                acc[mi].z += a.x * b0.z + a.y * b1.z + a.z * b2.z + a.w * b3.z;
                acc[mi].w += a.x * b0.w + a.y * b1.w + a.z * b2.w + a.w * b3.w;
            }
        }

        const int n = nh * 64 + tn * 4;
        const float4 bov = *(const float4*)(bo + n);
#pragma unroll
        for (int mi = 0; mi < 4; ++mi) {
            float4 v4 = acc[mi];
            v4.x += bov.x; v4.y += bov.y; v4.z += bov.z; v4.w += bov.w;
            const int pos = pos0 + tm * 4 + mi;
            *(float4*)(out + (size_t)pos * C_DIM + n) = v4;
        }
    }
}

// ---------------------------------------------------------------------------
extern "C" void kernel_launch(void* const* d_in, const int* in_sizes, int n_in,
                              void* d_out, int out_size, void* d_ws, size_t ws_size,
                              hipStream_t stream)
{
    const float* x     = (const float*)d_in[0];
    const float* mask  = (const float*)d_in[1];
    const float* ln_g  = (const float*)d_in[2];
    const float* ln_b  = (const float*)d_in[3];
    const float* w_tri = (const float*)d_in[4];
    const float* wq    = (const float*)d_in[5];
    const float* wk    = (const float*)d_in[6];
    const float* wv    = (const float*)d_in[7];
    const float* wg    = (const float*)d_in[8];
    const float* bg    = (const float*)d_in[9];
    const float* wo    = (const float*)d_in[10];
    const float* bo    = (const float*)d_in[11];
    float* out = (float*)d_out;
    char* ws = (char*)d_ws;

    const size_t NE = (size_t)NPOS * 128;            // elements per [I,H,J,D] buffer
    unsigned short* qb = (unsigned short*)ws;                    // bf16, 36 MiB
    unsigned short* kb = (unsigned short*)(ws + NE * 2);         // bf16
    unsigned short* vb = (unsigned short*)(ws + NE * 4);         // bf16
    float*          gb = (float*)(ws + NE * 6);                  // fp32 g -> og
    float*         tri = (float*)(ws + NE * 6 + NE * 4);         // fp32 [H][J][I]

    proj_kernel<<<NPOS / 64, 256, 0, stream>>>(x, ln_g, ln_b, w_tri, wq, wk, wv,
                                               wg, bg, qb, kb, vb, gb, tri);
    attn_kernel<<<I_DIM * H_DIM, 256, 0, stream>>>(qb, kb, vb, gb, tri, mask);
    out_kernel<<<NPOS / 64, 256, 0, stream>>>(gb, wo, bo, out);
}

// Round 5
// 523.404 us; speedup vs baseline: 5.0900x; 1.3905x over previous
//
#include <hip/hip_runtime.h>
#include <math.h>

// TriangleAttention: B=1, I=J=384, C=128, H=4, D=32, fp32 in/out.
//
// prep:  transpose 5 weight mats (wq,wk,wv,wg,wo) to bf16 [n][k] B-frag layout;
//        Q_SCALE folded into wq.
// proj:  LN (fp32) + tri bias; xn -> bf16 swizzled LDS A-tile; 4 MFMA GEMMs
//        (16x16x32 bf16) -> q,k,v bf16 [i][h][j][d]; g sigmoid'ed -> bf16.
// attn:  MFMA flash attention per (i,h) (unchanged from round 4, g/og bf16).
// out:   MFMA GEMM og[128 k = h*32+d] x woT -> out fp32 + bo.
//
// LDS swizzle: row-major [row][128 bf16], 16 chunks of 8 bf16; chunk stored at
// (c ^ (row&7)). All hot access phases are <=2-way bank aliased (free, m136).

#define I_DIM 384
#define J_DIM 384
#define C_DIM 128
#define H_DIM 4
#define D_DIM 32
#define NPOS (I_DIM * J_DIM)
#define Q_SCALE 0.17677669529663687f  // 1/sqrt(32)

typedef __attribute__((ext_vector_type(8))) short bf16x8;
typedef __attribute__((ext_vector_type(4))) float f32x4;

__device__ __forceinline__ float sigmoidf_(float v) {
    return 1.0f / (1.0f + __expf(-v));
}
__device__ __forceinline__ unsigned short f2bf(float f) {
    union { float f; unsigned u; } x; x.f = f;
    unsigned u = x.u;
    u += 0x7fffu + ((u >> 16) & 1u);
    return (unsigned short)(u >> 16);
}
__device__ __forceinline__ float bf2f(unsigned short v) {
    union { unsigned u; float f; } x; x.u = ((unsigned)v) << 16;
    return x.f;
}

// ---------------------------------------------------------------------------
// prep: Wt[mat][n][k] = W[k*128+n] (bf16), mat 0..4 = wq,wk,wv,wg,wo.
// ---------------------------------------------------------------------------
__global__ __launch_bounds__(256) void prep_kernel(
    const float* __restrict__ wq, const float* __restrict__ wk,
    const float* __restrict__ wv, const float* __restrict__ wg,
    const float* __restrict__ wo, unsigned short* __restrict__ Wt)
{
    const int mat = blockIdx.x;
    const float* W = (mat == 0) ? wq : (mat == 1) ? wk : (mat == 2) ? wv
                    : (mat == 3) ? wg : wo;
    const float scale = (mat == 0) ? Q_SCALE : 1.0f;
    const int t = threadIdx.x;
    const int n = t >> 1, c0 = (t & 1) * 64;
#pragma unroll
    for (int u = 0; u < 8; ++u) {
        unsigned pk[4];
#pragma unroll
        for (int w = 0; w < 4; ++w) {
            const unsigned short a = f2bf(W[(size_t)(c0 + u * 8 + w * 2 + 0) * 128 + n] * scale);
            const unsigned short b = f2bf(W[(size_t)(c0 + u * 8 + w * 2 + 1) * 128 + n] * scale);
            pk[w] = (unsigned)a | ((unsigned)b << 16);
        }
        int4 q; q.x = pk[0]; q.y = pk[1]; q.z = pk[2]; q.w = pk[3];
        *(int4*)(Wt + (size_t)mat * 16384 + n * 128 + c0 + u * 8) = q;
    }
}

// ---------------------------------------------------------------------------
// proj: grid = NPOS/128 = 1152, block = 256.  LDS 64KB -> 2 blocks/CU.
// ---------------------------------------------------------------------------
__global__ __launch_bounds__(256) void proj_kernel(
    const float* __restrict__ x, const float* __restrict__ ln_g,
    const float* __restrict__ ln_b, const float* __restrict__ w_tri,
    const unsigned short* __restrict__ Wt, const float* __restrict__ bg,
    unsigned short* __restrict__ qb, unsigned short* __restrict__ kb,
    unsigned short* __restrict__ vb, unsigned short* __restrict__ gb,
    float* __restrict__ tri)
{
    __shared__ unsigned short At[128 * 128];
    __shared__ unsigned short Bt[128 * 128];

    const int t = threadIdx.x;
    const int pos0 = blockIdx.x * 128;
    const int lane = t & 63, wave = t >> 6;
    const int q15 = lane & 15, quad = lane >> 4;

    // ---- LayerNorm + tri: thread (r = t>>1, half) owns 64 channels ----
    {
        const int r = t >> 1, half = t & 1, c0 = half * 64;
        const float* xrow = x + (size_t)(pos0 + r) * C_DIM + c0;
        float xv[64];
        float s = 0.f, ss = 0.f;
#pragma unroll
        for (int u = 0; u < 16; ++u) {
            float4 v4 = ((const float4*)xrow)[u];
            xv[u * 4 + 0] = v4.x; xv[u * 4 + 1] = v4.y;
            xv[u * 4 + 2] = v4.z; xv[u * 4 + 3] = v4.w;
            s  += v4.x + v4.y + v4.z + v4.w;
            ss += v4.x * v4.x + v4.y * v4.y + v4.z * v4.z + v4.w * v4.w;
        }
        s  += __shfl_xor(s, 1);
        ss += __shfl_xor(ss, 1);
        const float mu  = s * (1.0f / 128.0f);
        const float var = ss * (1.0f / 128.0f) - mu * mu;
        const float rstd = rsqrtf(var + 1e-5f);

        float ptri[4] = {0.f, 0.f, 0.f, 0.f};
#pragma unroll
        for (int u = 0; u < 8; ++u) {   // chunk of 8 channels
            const float4 g0 = ((const float4*)(ln_g + c0))[u * 2];
            const float4 g1 = ((const float4*)(ln_g + c0))[u * 2 + 1];
            const float4 b0 = ((const float4*)(ln_b + c0))[u * 2];
            const float4 b1 = ((const float4*)(ln_b + c0))[u * 2 + 1];
            float xn8[8];
            xn8[0] = (xv[u * 8 + 0] - mu) * rstd * g0.x + b0.x;
            xn8[1] = (xv[u * 8 + 1] - mu) * rstd * g0.y + b0.y;
            xn8[2] = (xv[u * 8 + 2] - mu) * rstd * g0.z + b0.z;
            xn8[3] = (xv[u * 8 + 3] - mu) * rstd * g0.w + b0.w;
            xn8[4] = (xv[u * 8 + 4] - mu) * rstd * g1.x + b1.x;
            xn8[5] = (xv[u * 8 + 5] - mu) * rstd * g1.y + b1.y;
            xn8[6] = (xv[u * 8 + 6] - mu) * rstd * g1.z + b1.z;
            xn8[7] = (xv[u * 8 + 7] - mu) * rstd * g1.w + b1.w;
#pragma unroll
            for (int w = 0; w < 8; ++w) {
                const float4 wt = ((const float4*)w_tri)[c0 + u * 8 + w];
                ptri[0] += xn8[w] * wt.x; ptri[1] += xn8[w] * wt.y;
                ptri[2] += xn8[w] * wt.z; ptri[3] += xn8[w] * wt.w;
            }
            unsigned pk[4];
#pragma unroll
            for (int w = 0; w < 4; ++w)
                pk[w] = (unsigned)f2bf(xn8[w * 2]) | ((unsigned)f2bf(xn8[w * 2 + 1]) << 16);
            int4 q4; q4.x = pk[0]; q4.y = pk[1]; q4.z = pk[2]; q4.w = pk[3];
            const int c = half * 8 + u;
            *(int4*)&At[r * 128 + ((c ^ (r & 7)) * 8)] = q4;
        }
#pragma unroll
        for (int hh = 0; hh < 4; ++hh) ptri[hh] += __shfl_xor(ptri[hh], 1);
        const int pos = pos0 + r;
        const int i = pos / J_DIM, j = pos - (pos / J_DIM) * J_DIM;
        const int h0 = half * 2;
        tri[((size_t)(h0 + 0) * J_DIM + j) * I_DIM + i] = ptri[h0 + 0];
        tri[((size_t)(h0 + 1) * J_DIM + j) * I_DIM + i] = ptri[h0 + 1];
    }

    const int m0 = wave * 32;
    for (int mat = 0; mat < 4; ++mat) {
        __syncthreads();
        // ---- stage B-tile (swizzled) ----
        {
            const int rn = t >> 1, half = t & 1;
            const unsigned short* src = Wt + (size_t)mat * 16384 + rn * 128 + half * 64;
#pragma unroll
            for (int u = 0; u < 8; ++u) {
                const int c = half * 8 + u;
                *(int4*)&Bt[rn * 128 + ((c ^ (rn & 7)) * 8)] = *(const int4*)(src + u * 8);
            }
        }
        __syncthreads();

        f32x4 acc[2][8];
#pragma unroll
        for (int mt = 0; mt < 2; ++mt)
#pragma unroll
            for (int nt = 0; nt < 8; ++nt) acc[mt][nt] = (f32x4){0.f, 0.f, 0.f, 0.f};

#pragma unroll
        for (int kk = 0; kk < 4; ++kk) {
            // all hot rows are ≡ q15 (mod 16) -> row&7 == q15&7 -> common swizzle
            const int sw = ((kk * 4 + quad) ^ (q15 & 7)) * 8;
            const bf16x8 a0 = *(const bf16x8*)&At[(m0 + q15) * 128 + sw];
            const bf16x8 a1 = *(const bf16x8*)&At[(m0 + 16 + q15) * 128 + sw];
#pragma unroll
            for (int nt = 0; nt < 8; ++nt) {
                const bf16x8 b = *(const bf16x8*)&Bt[(nt * 16 + q15) * 128 + sw];
                acc[0][nt] = __builtin_amdgcn_mfma_f32_16x16x32_bf16(a0, b, acc[0][nt], 0, 0, 0);
                acc[1][nt] = __builtin_amdgcn_mfma_f32_16x16x32_bf16(a1, b, acc[1][nt], 0, 0, 0);
            }
        }

        // ---- epilogue: C -> Bt (bf16, swizzled) -> vectorized global ----
        __syncthreads();
#pragma unroll
        for (int mt = 0; mt < 2; ++mt)
#pragma unroll
            for (int nt = 0; nt < 8; ++nt) {
                const int col = nt * 16 + q15;
                const float bgl = (mat == 3) ? bg[col] : 0.f;
#pragma unroll
                for (int reg = 0; reg < 4; ++reg) {
                    float v = acc[mt][nt][reg];
                    if (mat == 3) v = sigmoidf_(v + bgl);
                    const int row = m0 + mt * 16 + quad * 4 + reg;
                    Bt[row * 128 + (((col >> 3) ^ (row & 7)) * 8) + (col & 7)] = f2bf(v);
                }
            }
        __syncthreads();
        {
            unsigned short* O = (mat == 0) ? qb : (mat == 1) ? kb : (mat == 2) ? vb : gb;
#pragma unroll
            for (int sgm = 0; sgm < 2; ++sgm) {
                const int ch = t + sgm * 256;       // 512 chunks = 128 rows x 4 heads
                const int r = ch >> 2, hh = ch & 3;
                const int pos = pos0 + r;
                const int i = pos / J_DIM, j = pos - (pos / J_DIM) * J_DIM;
                unsigned short* dst = O + (((size_t)i * H_DIM + hh) * J_DIM + j) * D_DIM;
#pragma unroll
                for (int w = 0; w < 4; ++w) {
                    const int c = hh * 4 + w;
                    *(int4*)(dst + w * 8) = *(const int4*)&Bt[r * 128 + ((c ^ (r & 7)) * 8)];
                }
            }
        }
    }
}

// ---------------------------------------------------------------------------
// attn: MFMA flash attention (round-4 structure; g/og bf16).
// grid = I*H = 1536, block = 256 (4 waves).
// ---------------------------------------------------------------------------
__global__ __launch_bounds__(256) void attn_kernel(
    const unsigned short* __restrict__ qb, const unsigned short* __restrict__ kb,
    const unsigned short* __restrict__ vb, unsigned short* gob,
    const float* __restrict__ triT, const float* __restrict__ mask)
{
    __shared__ unsigned short Klds[64 * 32];
    __shared__ unsigned short Vt[32 * 68];
    __shared__ unsigned short Plds[4][96 * 68];
    __shared__ float Mb[J_DIM];

    const int t = threadIdx.x;
    const int lane = t & 63, wave = t >> 6;
    const int q15 = lane & 15, quad = lane >> 4;
    const int i = blockIdx.x >> 2, h = blockIdx.x & 3;
    const size_t hb = (size_t)(i * H_DIM + h) * (J_DIM * D_DIM);
    const int m0 = wave * 96;

    for (int idx = t; idx < J_DIM; idx += 256)
        Mb[idx] = 1.0e9f * (mask[i * J_DIM + idx] - 1.0f);

    bf16x8 qf[6];
#pragma unroll
    for (int m = 0; m < 6; ++m)
        qf[m] = *(const bf16x8*)(qb + hb + (size_t)(m0 + m * 16 + q15) * D_DIM + quad * 8);

    f32x4 Oacc[6][2];
    float sums[6][4];
#pragma unroll
    for (int m = 0; m < 6; ++m) {
#pragma unroll
        for (int d2 = 0; d2 < 2; ++d2) Oacc[m][d2] = (f32x4){0.f, 0.f, 0.f, 0.f};
#pragma unroll
        for (int r = 0; r < 4; ++r) sums[m][r] = 0.f;
    }

    unsigned short* Pw = Plds[wave];
    const float* triH = triT + (size_t)h * J_DIM * I_DIM;

    for (int kt = 0; kt < 6; ++kt) {
        __syncthreads();
        {
            const int kp = t >> 2, du = (t & 3) * 8;
            const size_t gsrc = hb + (size_t)(kt * 64 + kp) * D_DIM + du;
            *(int4*)&Klds[kp * 32 + du] = *(const int4*)(kb + gsrc);
            int4 vv = *(const int4*)(vb + gsrc);
            const unsigned short* vs = (const unsigned short*)&vv;
#pragma unroll
            for (int u = 0; u < 8; ++u)
                Vt[(du + u) * 68 + kp] = vs[u];
        }
        __syncthreads();

#pragma unroll
        for (int nt = 0; nt < 4; ++nt) {
            const bf16x8 kf = *(const bf16x8*)&Klds[(nt * 16 + q15) * 32 + quad * 8];
            const float mb = Mb[kt * 64 + nt * 16 + q15];
            const float* tcol = triH + (size_t)(kt * 64 + nt * 16 + q15) * I_DIM;
#pragma unroll
            for (int m = 0; m < 6; ++m) {
                const float4 tb = *(const float4*)(tcol + m0 + m * 16 + quad * 4);
                f32x4 s = {0.f, 0.f, 0.f, 0.f};
                s = __builtin_amdgcn_mfma_f32_16x16x32_bf16(qf[m], kf, s, 0, 0, 0);
                const float p0 = __expf(s[0] + mb + tb.x);
                const float p1 = __expf(s[1] + mb + tb.y);
                const float p2 = __expf(s[2] + mb + tb.z);
                const float p3 = __expf(s[3] + mb + tb.w);
                sums[m][0] += p0; sums[m][1] += p1;
                sums[m][2] += p2; sums[m][3] += p3;
                const int row = m * 16 + quad * 4;
                const int col = nt * 16 + q15;
                Pw[(row + 0) * 68 + col] = f2bf(p0);
                Pw[(row + 1) * 68 + col] = f2bf(p1);
                Pw[(row + 2) * 68 + col] = f2bf(p2);
                Pw[(row + 3) * 68 + col] = f2bf(p3);
            }
        }

        bf16x8 vf[2][2];
#pragma unroll
        for (int ks = 0; ks < 2; ++ks)
#pragma unroll
            for (int d2 = 0; d2 < 2; ++d2)
                vf[ks][d2] = *(const bf16x8*)&Vt[(d2 * 16 + q15) * 68 + ks * 32 + quad * 8];
#pragma unroll
        for (int m = 0; m < 6; ++m) {
#pragma unroll
            for (int ks = 0; ks < 2; ++ks) {
                const bf16x8 af = *(const bf16x8*)&Pw[(m * 16 + q15) * 68 + ks * 32 + quad * 8];
                Oacc[m][0] = __builtin_amdgcn_mfma_f32_16x16x32_bf16(af, vf[ks][0], Oacc[m][0], 0, 0, 0);
                Oacc[m][1] = __builtin_amdgcn_mfma_f32_16x16x32_bf16(af, vf[ks][1], Oacc[m][1], 0, 0, 0);
            }
        }
    }

    float inv[6][4];
#pragma unroll
    for (int m = 0; m < 6; ++m)
#pragma unroll
        for (int r = 0; r < 4; ++r) {
            float s0 = sums[m][r];
            s0 += __shfl_xor(s0, 1); s0 += __shfl_xor(s0, 2);
            s0 += __shfl_xor(s0, 4); s0 += __shfl_xor(s0, 8);
            inv[m][r] = 1.0f / s0;
        }

#pragma unroll
    for (int m = 0; m < 6; ++m) {
        const int qrow = m0 + m * 16 + quad * 4;
#pragma unroll
        for (int d2 = 0; d2 < 2; ++d2) {
            const int d = d2 * 16 + q15;
#pragma unroll
            for (int r = 0; r < 4; ++r) {
                const size_t idx = hb + (size_t)(qrow + r) * D_DIM + d;
                const float g = bf2f(gob[idx]);
                gob[idx] = f2bf(Oacc[m][d2][r] * inv[m][r] * g);
            }
        }
    }
}

// ---------------------------------------------------------------------------
// out: MFMA GEMM.  grid = NPOS/128 = 1152, block = 256.
// ---------------------------------------------------------------------------
__global__ __launch_bounds__(256) void out_kernel(
    const unsigned short* __restrict__ og, const unsigned short* __restrict__ WtO,
    const float* __restrict__ bo, float* __restrict__ out)
{
    __shared__ unsigned short At[128 * 128];
    __shared__ unsigned short Bt[128 * 128];

    const int t = threadIdx.x;
    const int pos0 = blockIdx.x * 128;
    const int lane = t & 63, wave = t >> 6;
    const int q15 = lane & 15, quad = lane >> 4;

    {
        const int r = t >> 1, half = t & 1;
        const int pos = pos0 + r;
        const int i = pos / J_DIM, j = pos - (pos / J_DIM) * J_DIM;
#pragma unroll
        for (int u = 0; u < 8; ++u) {
            const int k0 = half * 64 + u * 8;
            const int hh = k0 >> 5, d0 = k0 & 31;
            const int4 v = *(const int4*)(og + (((size_t)i * H_DIM + hh) * J_DIM + j) * D_DIM + d0);
            const int c = half * 8 + u;
            *(int4*)&At[r * 128 + ((c ^ (r & 7)) * 8)] = v;
        }
        const unsigned short* src = WtO + r * 128 + half * 64;
#pragma unroll
        for (int u = 0; u < 8; ++u) {
            const int c = half * 8 + u;
            *(int4*)&Bt[r * 128 + ((c ^ (r & 7)) * 8)] = *(const int4*)(src + u * 8);
        }
    }
    __syncthreads();

    const int m0 = wave * 32;
    f32x4 acc[2][8];
#pragma unroll
    for (int mt = 0; mt < 2; ++mt)
#pragma unroll
        for (int nt = 0; nt < 8; ++nt) acc[mt][nt] = (f32x4){0.f, 0.f, 0.f, 0.f};

#pragma unroll
    for (int kk = 0; kk < 4; ++kk) {
        const int sw = ((kk * 4 + quad) ^ (q15 & 7)) * 8;
        const bf16x8 a0 = *(const bf16x8*)&At[(m0 + q15) * 128 + sw];
        const bf16x8 a1 = *(const bf16x8*)&At[(m0 + 16 + q15) * 128 + sw];
#pragma unroll
        for (int nt = 0; nt < 8; ++nt) {
            const bf16x8 b = *(const bf16x8*)&Bt[(nt * 16 + q15) * 128 + sw];
            acc[0][nt] = __builtin_amdgcn_mfma_f32_16x16x32_bf16(a0, b, acc[0][nt], 0, 0, 0);
            acc[1][nt] = __builtin_amdgcn_mfma_f32_16x16x32_bf16(a1, b, acc[1][nt], 0, 0, 0);
        }
    }

#pragma unroll
    for (int mt = 0; mt < 2; ++mt)
#pragma unroll
        for (int nt = 0; nt < 8; ++nt) {
            const float bov = bo[nt * 16 + q15];
#pragma unroll
            for (int reg = 0; reg < 4; ++reg) {
                const int pos = pos0 + m0 + mt * 16 + quad * 4 + reg;
                out[(size_t)pos * C_DIM + nt * 16 + q15] = acc[mt][nt][reg] + bov;
            }
        }
}

// ---------------------------------------------------------------------------
extern "C" void kernel_launch(void* const* d_in, const int* in_sizes, int n_in,
                              void* d_out, int out_size, void* d_ws, size_t ws_size,
                              hipStream_t stream)
{
    const float* x     = (const float*)d_in[0];
    const float* mask  = (const float*)d_in[1];
    const float* ln_g  = (const float*)d_in[2];
    const float* ln_b  = (const float*)d_in[3];
    const float* w_tri = (const float*)d_in[4];
    const float* wq    = (const float*)d_in[5];
    const float* wk    = (const float*)d_in[6];
    const float* wv    = (const float*)d_in[7];
    const float* wg    = (const float*)d_in[8];
    const float* bg    = (const float*)d_in[9];
    const float* wo    = (const float*)d_in[10];
    const float* bo    = (const float*)d_in[11];
    float* out = (float*)d_out;
    char* ws = (char*)d_ws;

    const size_t NE = (size_t)NPOS * 128;   // elements per [I,H,J,D] buffer
    unsigned short* qb = (unsigned short*)ws;                     // bf16 36 MiB
    unsigned short* kb = (unsigned short*)(ws + NE * 2);
    unsigned short* vb = (unsigned short*)(ws + NE * 4);
    unsigned short* gb = (unsigned short*)(ws + NE * 6);          // g -> og
    float*         tri = (float*)(ws + NE * 8);                   // [H][J][I]
    unsigned short* Wt = (unsigned short*)(ws + NE * 8 + (size_t)NPOS * 4 * 4);

    prep_kernel<<<5, 256, 0, stream>>>(wq, wk, wv, wg, wo, Wt);
    proj_kernel<<<NPOS / 128, 256, 0, stream>>>(x, ln_g, ln_b, w_tri, Wt, bg,
                                                qb, kb, vb, gb, tri);
    attn_kernel<<<I_DIM * H_DIM, 256, 0, stream>>>(qb, kb, vb, gb, tri, mask);
    out_kernel<<<NPOS / 128, 256, 0, stream>>>(gb, Wt + 4 * 16384, bo, out);
}